// Round 10
// baseline (367.747 us; speedup 1.0000x reference)
//
#include <hip/hip_runtime.h>
#include <hip/hip_bf16.h>

#define DIMN 2048
#define NQKV 6144
#define NH 16
#define HD 128
#define BSZ 2
#define SEQ 2048
#define ROWS (BSZ*SEQ)   // 4096

typedef short short8 __attribute__((ext_vector_type(8)));
typedef float f32x4 __attribute__((ext_vector_type(4)));

__device__ __forceinline__ unsigned short f2bf(float f) {
    __hip_bfloat16 h = __float2bfloat16(f);
    unsigned short u; __builtin_memcpy(&u, &h, 2); return u;
}

__device__ __forceinline__ void gld_lds16(const void* g, void* l) {
    __builtin_amdgcn_global_load_lds(
        (const __attribute__((address_space(1))) void*)g,
        (__attribute__((address_space(3))) void*)l, 16, 0, 0);
}

// ---------------- fused f32 -> bf16 converts ----------------
__global__ void cvt_all(const float* __restrict__ x, const float* __restrict__ wq,
                        const float* __restrict__ wk, const float* __restrict__ wv,
                        const float* __restrict__ wo,
                        unsigned short* __restrict__ Xb, unsigned short* __restrict__ Wcat,
                        unsigned short* __restrict__ Wo2) {
    int bid = blockIdx.x;
    const float* in; unsigned short* out; int base;
    if      (bid <  8192) { in = x;  out = Xb;             base = bid; }
    else if (bid < 12288) { in = wq; out = Wcat;           base = bid - 8192; }
    else if (bid < 16384) { in = wk; out = Wcat + 4194304; base = bid - 12288; }
    else if (bid < 20480) { in = wv; out = Wcat + 8388608; base = bid - 16384; }
    else                  { in = wo; out = Wo2;            base = bid - 20480; }
    int i = (base * 256 + threadIdx.x) * 4;
    float4 v = *(const float4*)(in + i);
    ushort4 o; o.x = f2bf(v.x); o.y = f2bf(v.y); o.z = f2bf(v.z); o.w = f2bf(v.w);
    *(ushort4*)(out + i) = o;
}

// ================= 256x256 8-phase GEMM (UNCHANGED from r8 — reference "full") ===========
template<int MODE>
__global__ __launch_bounds__(512, 2) void gemm256(
    const unsigned short* __restrict__ A, int lda,
    const unsigned short* __restrict__ B, int ldb,
    const float* __restrict__ b0, const float* __restrict__ b1, const float* __restrict__ b2,
    const float* __restrict__ fcos, const float* __restrict__ fsin,
    void* __restrict__ C, int ldc, int K)
{
    __shared__ __align__(16) unsigned short As[32768];  // 64 KB: [2buf][2half][128][64]
    __shared__ __align__(16) unsigned short Bs[32768];  // 64 KB

    const int t  = threadIdx.x;
    const int l  = t & 63;
    const int w  = t >> 6;
    const int wr = w >> 2;          // 0..1
    const int wc = w & 3;           // 0..3
    const int fr = l & 15, fq = l >> 4;

    const int xcd = blockIdx.x & 7;
    const int j   = blockIdx.x >> 3;
    int mt, nt;
    if (MODE == 0) {
        if (j < 32) { mt = (xcd & 1) * 8 + (j >> 2); nt = (xcd >> 1) * 4 + (j & 3); }
        else { const int p = j - 32, c = xcd >> 1;
               mt = (c & 1) * 8 + (xcd & 1) * 4 + (p >> 2); nt = (4 + (c >> 1)) * 4 + (p & 3); }
    } else {
        mt = (xcd >> 1) * 4 + (j >> 2);
        nt = (xcd & 1) * 4 + (j & 3);
    }
    const int m0 = mt * 256;
    const int n0 = nt * 256;

    const unsigned short* Bsel = B;
    if (MODE == 1 && m0 >= 2048) Bsel += (size_t)2048 * 2048;  // per-batch W2

    const int srow = t >> 3;                        // 0..63
    const int scol = ((t & 7) ^ (srow & 7)) * 8;
    const unsigned short* aS = A    + (size_t)(m0 + srow) * lda + scol;
    const unsigned short* bS = Bsel + (size_t)(n0 + srow) * ldb + scol;

#define STG_A(KT, H) do { \
    const unsigned short* s_ = aS + (size_t)(H) * 128 * lda + (size_t)(KT) * 64; \
    gld_lds16(s_,                    &As[(((KT) & 1) << 14) + ((H) << 13) + t * 8]); \
    gld_lds16(s_ + (size_t)64 * lda, &As[(((KT) & 1) << 14) + ((H) << 13) + 4096 + t * 8]); \
  } while (0)
#define STG_B(KT, H) do { \
    const unsigned short* s_ = bS + (size_t)(H) * 128 * ldb + (size_t)(KT) * 64; \
    gld_lds16(s_,                    &Bs[(((KT) & 1) << 14) + ((H) << 13) + t * 8]); \
    gld_lds16(s_ + (size_t)64 * ldb, &Bs[(((KT) & 1) << 14) + ((H) << 13) + 4096 + t * 8]); \
  } while (0)

    const int cK0 = (fq ^ (fr & 7)) * 8;
    const int cK1 = ((4 + fq) ^ (fr & 7)) * 8;
    const int aB0 = wr * 8192 + fr * 64;
    const int bB0 = wc * 4096 + fr * 64;

    const unsigned aA0 = (unsigned)(size_t)&As[aB0 + cK0];
    const unsigned aA1 = (unsigned)(size_t)&As[aB0 + cK1];
    const unsigned bA0 = (unsigned)(size_t)&Bs[bB0 + cK0];
    const unsigned bA1 = (unsigned)(size_t)&Bs[bB0 + cK1];

    short8 aF[4][2], bF0[2][2], bF1[2][2];
    f32x4  acc[8][4] = {};

#define DSR(dst, areg, OFF) \
    asm volatile("ds_read_b128 %0, %1 offset:%2" : "=v"(dst) : "v"(areg), "n"(OFF))

#define RD_A(DDB, QM) do { \
    DSR(aF[0][0], aA0, (DDB) + (QM) * 8192 + 0);    DSR(aF[0][1], aA1, (DDB) + (QM) * 8192 + 0); \
    DSR(aF[1][0], aA0, (DDB) + (QM) * 8192 + 2048); DSR(aF[1][1], aA1, (DDB) + (QM) * 8192 + 2048); \
    DSR(aF[2][0], aA0, (DDB) + (QM) * 8192 + 4096); DSR(aF[2][1], aA1, (DDB) + (QM) * 8192 + 4096); \
    DSR(aF[3][0], aA0, (DDB) + (QM) * 8192 + 6144); DSR(aF[3][1], aA1, (DDB) + (QM) * 8192 + 6144); \
  } while (0)
#define RD_B(DDB, QN, BF) do { \
    DSR(BF[0][0], bA0, (DDB) + (QN) * 4096 + 0);    DSR(BF[0][1], bA1, (DDB) + (QN) * 4096 + 0); \
    DSR(BF[1][0], bA0, (DDB) + (QN) * 4096 + 2048); DSR(BF[1][1], bA1, (DDB) + (QN) * 4096 + 2048); \
  } while (0)

#define BAR() asm volatile("s_barrier" ::: "memory")

#define MM(QM, QN, BF) do { \
    asm volatile("s_waitcnt lgkmcnt(0)"); \
    __builtin_amdgcn_sched_barrier(0); \
    __builtin_amdgcn_s_setprio(1); \
    _Pragma("unroll") for (int m2 = 0; m2 < 4; ++m2) \
      _Pragma("unroll") for (int n2 = 0; n2 < 2; ++n2) { \
        acc[(QM)*4+m2][(QN)*2+n2] = __builtin_amdgcn_mfma_f32_16x16x32_bf16( \
            aF[m2][0], BF[n2][0], acc[(QM)*4+m2][(QN)*2+n2], 0, 0, 0); \
        acc[(QM)*4+m2][(QN)*2+n2] = __builtin_amdgcn_mfma_f32_16x16x32_bf16( \
            aF[m2][1], BF[n2][1], acc[(QM)*4+m2][(QN)*2+n2], 0, 0, 0); } \
    __builtin_amdgcn_s_setprio(0); \
    __builtin_amdgcn_sched_barrier(0); \
  } while (0)

#define TILE(KT, DDB) do { \
    const bool sA = (KT) + 1 < ktT; \
    const bool sB = (KT) + 2 < ktT; \
    RD_A(DDB, 0); RD_B(DDB, 0, bF0); \
    if (sA) STG_A((KT) + 1, 0); \
    asm volatile("s_waitcnt lgkmcnt(8)"); \
    BAR(); \
    MM(0, 0, bF0); \
    BAR(); \
    RD_B(DDB, 1, bF1); \
    if (sA) STG_A((KT) + 1, 1); \
    BAR(); \
    MM(0, 1, bF1); \
    BAR(); \
    RD_A(DDB, 1); \
    if (sB) STG_B((KT) + 2, 0); \
    BAR(); \
    MM(1, 0, bF0); \
    BAR(); \
    if (sB) STG_B((KT) + 2, 1); \
    MM(1, 1, bF1); \
    if ((KT) < ktT - 2) { asm volatile("s_waitcnt vmcnt(4)"); } \
    else                { asm volatile("s_waitcnt vmcnt(0)"); } \
    __builtin_amdgcn_sched_barrier(0); \
    BAR(); \
  } while (0)

    const int ktT = K >> 6;   // 32

    STG_A(0, 0); STG_A(0, 1);
    STG_B(0, 0); STG_B(0, 1);
    STG_B(1, 0); STG_B(1, 1);
    asm volatile("s_waitcnt vmcnt(4)");
    __builtin_amdgcn_sched_barrier(0);
    BAR();

    for (int kt = 0; kt < ktT; kt += 2) {
        TILE(kt, 0);
        TILE(kt + 1, 32768);
    }

#undef TILE
#undef MM
#undef BAR
#undef RD_A
#undef RD_B
#undef DSR
#undef STG_A
#undef STG_B

    #pragma unroll
    for (int mi = 0; mi < 8; ++mi) {
        #pragma unroll
        for (int ni = 0; ni < 4; ++ni) {
            #pragma unroll
            for (int j2 = 0; j2 < 4; ++j2) {
                const int r  = m0 + wr * 128 + mi * 16 + fq * 4 + j2;
                const int cg = n0 + wc * 64 + ni * 16 + fr;
                float v = acc[mi][ni][j2];
                if (MODE == 0) {
                    v += (cg < 2048) ? b0[cg] : ((cg < 4096) ? b1[cg - 2048] : b2[cg - 4096]);
                    if (cg < 4096) {
                        const int s = r & (SEQ - 1);
                        const int i = (cg >> 1) & 63;
                        const float cs = fcos[s * 64 + i];
                        const float sn = fsin[s * 64 + i];
                        const float p  = __shfl_xor(v, 1);
                        v = (fr & 1) ? (p * sn + v * cs) : (v * cs - p * sn);
                    }
                    ((unsigned short*)C)[(size_t)r * ldc + cg] = f2bf(v);
                } else {
                    v += b0[cg];
                    ((float*)C)[(size_t)r * ldc + cg] = v;
                }
            }
        }
    }
}

// ================= ABLATION A: staging path only (r8 skeleton, RD/MFMA deleted) ==========
__global__ __launch_bounds__(512, 2) void abl_stage(
    const unsigned short* __restrict__ A, int lda,
    const unsigned short* __restrict__ B, int ldb)
{
    __shared__ __align__(16) unsigned short As[32768];
    __shared__ __align__(16) unsigned short Bs[32768];

    const int t = threadIdx.x;
    const int xcd = blockIdx.x & 7;
    const int j   = blockIdx.x >> 3;
    int mt, nt;
    if (j < 32) { mt = (xcd & 1) * 8 + (j >> 2); nt = (xcd >> 1) * 4 + (j & 3); }
    else { const int p = j - 32, c = xcd >> 1;
           mt = (c & 1) * 8 + (xcd & 1) * 4 + (p >> 2); nt = (4 + (c >> 1)) * 4 + (p & 3); }
    const int m0 = mt * 256, n0 = nt * 256;

    const int srow = t >> 3;
    const int scol = ((t & 7) ^ (srow & 7)) * 8;
    const unsigned short* aS = A + (size_t)(m0 + srow) * lda + scol;
    const unsigned short* bS = B + (size_t)(n0 + srow) * ldb + scol;

#define SG_A(KT, H) do { \
    const unsigned short* s_ = aS + (size_t)(H) * 128 * lda + (size_t)(KT) * 64; \
    gld_lds16(s_,                    &As[(((KT) & 1) << 14) + ((H) << 13) + t * 8]); \
    gld_lds16(s_ + (size_t)64 * lda, &As[(((KT) & 1) << 14) + ((H) << 13) + 4096 + t * 8]); \
  } while (0)
#define SG_B(KT, H) do { \
    const unsigned short* s_ = bS + (size_t)(H) * 128 * ldb + (size_t)(KT) * 64; \
    gld_lds16(s_,                    &Bs[(((KT) & 1) << 14) + ((H) << 13) + t * 8]); \
    gld_lds16(s_ + (size_t)64 * ldb, &Bs[(((KT) & 1) << 14) + ((H) << 13) + 4096 + t * 8]); \
  } while (0)
#define ABAR() asm volatile("s_barrier" ::: "memory")

    const int ktT = 32;
    SG_A(0, 0); SG_A(0, 1);
    SG_B(0, 0); SG_B(0, 1);
    SG_B(1, 0); SG_B(1, 1);
    asm volatile("s_waitcnt vmcnt(4)");
    ABAR();

    for (int kt = 0; kt < ktT; ++kt) {
        const bool sA = kt + 1 < ktT;
        const bool sB = kt + 2 < ktT;
        if (sA) SG_A(kt + 1, 0);
        ABAR(); ABAR();
        if (sA) SG_A(kt + 1, 1);
        ABAR(); ABAR();
        if (sB) SG_B(kt + 2, 0);
        ABAR(); ABAR();
        if (sB) SG_B(kt + 2, 1);
        if (kt < ktT - 2) { asm volatile("s_waitcnt vmcnt(4)"); }
        else              { asm volatile("s_waitcnt vmcnt(0)"); }
        ABAR();
    }
#undef ABAR
#undef SG_A
#undef SG_B
}

// ================= ABLATION B: compute path only (r8 skeleton, staging deleted) ==========
// NOTE: loop body instantiated twice with LITERAL buffer offsets (asm "n" constraint).
__global__ __launch_bounds__(512, 2) void abl_comp(float* __restrict__ sink)
{
    __shared__ __align__(16) unsigned short As[32768];
    __shared__ __align__(16) unsigned short Bs[32768];

    const int t  = threadIdx.x;
    const int l  = t & 63;
    const int w  = t >> 6;
    const int wr = w >> 2;
    const int wc = w & 3;
    const int fr = l & 15, fq = l >> 4;

    const int cK0 = (fq ^ (fr & 7)) * 8;
    const int cK1 = ((4 + fq) ^ (fr & 7)) * 8;
    const int aB0 = wr * 8192 + fr * 64;
    const int bB0 = wc * 4096 + fr * 64;

    const unsigned aA0 = (unsigned)(size_t)&As[aB0 + cK0];
    const unsigned aA1 = (unsigned)(size_t)&As[aB0 + cK1];
    const unsigned bA0 = (unsigned)(size_t)&Bs[bB0 + cK0];
    const unsigned bA1 = (unsigned)(size_t)&Bs[bB0 + cK1];

    short8 aF[4][2], bF0[2][2], bF1[2][2];
    f32x4  acc[8][4] = {};

#define DSR2(dst, areg, OFF) \
    asm volatile("ds_read_b128 %0, %1 offset:%2" : "=v"(dst) : "v"(areg), "n"(OFF))
#define RA(DDB, QM) do { \
    DSR2(aF[0][0], aA0, (DDB) + (QM) * 8192 + 0);    DSR2(aF[0][1], aA1, (DDB) + (QM) * 8192 + 0); \
    DSR2(aF[1][0], aA0, (DDB) + (QM) * 8192 + 2048); DSR2(aF[1][1], aA1, (DDB) + (QM) * 8192 + 2048); \
    DSR2(aF[2][0], aA0, (DDB) + (QM) * 8192 + 4096); DSR2(aF[2][1], aA1, (DDB) + (QM) * 8192 + 4096); \
    DSR2(aF[3][0], aA0, (DDB) + (QM) * 8192 + 6144); DSR2(aF[3][1], aA1, (DDB) + (QM) * 8192 + 6144); \
  } while (0)
#define RB(DDB, QN, BF) do { \
    DSR2(BF[0][0], bA0, (DDB) + (QN) * 4096 + 0);    DSR2(BF[0][1], bA1, (DDB) + (QN) * 4096 + 0); \
    DSR2(BF[1][0], bA0, (DDB) + (QN) * 4096 + 2048); DSR2(BF[1][1], bA1, (DDB) + (QN) * 4096 + 2048); \
  } while (0)
#define CBAR() asm volatile("s_barrier" ::: "memory")
#define CMM(QM, QN, BF) do { \
    asm volatile("s_waitcnt lgkmcnt(0)"); \
    __builtin_amdgcn_sched_barrier(0); \
    __builtin_amdgcn_s_setprio(1); \
    _Pragma("unroll") for (int m2 = 0; m2 < 4; ++m2) \
      _Pragma("unroll") for (int n2 = 0; n2 < 2; ++n2) { \
        acc[(QM)*4+m2][(QN)*2+n2] = __builtin_amdgcn_mfma_f32_16x16x32_bf16( \
            aF[m2][0], BF[n2][0], acc[(QM)*4+m2][(QN)*2+n2], 0, 0, 0); \
        acc[(QM)*4+m2][(QN)*2+n2] = __builtin_amdgcn_mfma_f32_16x16x32_bf16( \
            aF[m2][1], BF[n2][1], acc[(QM)*4+m2][(QN)*2+n2], 0, 0, 0); } \
    __builtin_amdgcn_s_setprio(0); \
    __builtin_amdgcn_sched_barrier(0); \
  } while (0)
#define CTILE(DDB) do { \
    RA(DDB, 0); RB(DDB, 0, bF0); \
    asm volatile("s_waitcnt lgkmcnt(8)"); \
    CBAR(); \
    CMM(0, 0, bF0); \
    CBAR(); \
    RB(DDB, 1, bF1); \
    CBAR(); \
    CMM(0, 1, bF1); \
    CBAR(); \
    RA(DDB, 1); \
    CBAR(); \
    CMM(1, 0, bF0); \
    CBAR(); \
    CMM(1, 1, bF1); \
    CBAR(); \
  } while (0)

    CBAR();
    for (int kt = 0; kt < 16; ++kt) {   // 16 x 2 tiles = 32 K-tiles, literal buffer offsets
        CTILE(0);
        CTILE(32768);
    }
#undef CTILE
#undef CMM
#undef CBAR
#undef RA
#undef RB
#undef DSR2

    float s = 0.f;
    #pragma unroll
    for (int mi = 0; mi < 8; ++mi)
        #pragma unroll
        for (int ni = 0; ni < 4; ++ni)
            #pragma unroll
            for (int j2 = 0; j2 < 4; ++j2) s += acc[mi][ni][j2];
    sink[(size_t)blockIdx.x * 512 + t] = s;
}

// ---------------- 128x128 GEMM core (small GEMMs) ----------------
template<int OUT_BF16, int HAS_BIAS>
__device__ __forceinline__ void gemm_tile_core(
    const unsigned short* __restrict__ A, int lda,
    const unsigned short* __restrict__ B, int ldb,
    const float* __restrict__ bias,
    void* __restrict__ Cptr, int ldc, int K)
{
    __shared__ __align__(16) unsigned short As[128 * 64];
    __shared__ __align__(16) unsigned short Bs[128 * 64];

    const int t  = threadIdx.x;
    const int l  = t & 63;
    const int w  = t >> 6;
    const int wr = w >> 1, wc = w & 1;
    const int fr = l & 15, fq = l >> 4;

    f32x4 acc[4][4] = {};

    const int srow = t >> 3;
    const int scol = (t & 7) * 8;

    for (int k0 = 0; k0 < K; k0 += 64) {
        __syncthreads();
        #pragma unroll
        for (int r = 0; r < 4; ++r) {
            gld_lds16(A + (size_t)(r * 32 + srow) * lda + k0 + scol, &As[(r * 32 + srow) * 64 + scol]);
            gld_lds16(B + (size_t)(r * 32 + srow) * ldb + k0 + scol, &Bs[(r * 32 + srow) * 64 + scol]);
        }
        __syncthreads();
        #pragma unroll
        for (int kk = 0; kk < 2; ++kk) {
            short8 a[4], b[4];
            #pragma unroll
            for (int mi = 0; mi < 4; ++mi)
                a[mi] = *(const short8*)&As[(wr * 64 + mi * 16 + fr) * 64 + kk * 32 + fq * 8];
            #pragma unroll
            for (int ni = 0; ni < 4; ++ni)
                b[ni] = *(const short8*)&Bs[(wc * 64 + ni * 16 + fr) * 64 + kk * 32 + fq * 8];
            #pragma unroll
            for (int mi = 0; mi < 4; ++mi)
                #pragma unroll
                for (int ni = 0; ni < 4; ++ni)
                    acc[mi][ni] = __builtin_amdgcn_mfma_f32_16x16x32_bf16(a[mi], b[ni], acc[mi][ni], 0, 0, 0);
        }
    }

    #pragma unroll
    for (int mi = 0; mi < 4; ++mi) {
        #pragma unroll
        for (int ni = 0; ni < 4; ++ni) {
            #pragma unroll
            for (int j = 0; j < 4; ++j) {
                int rr = wr * 64 + mi * 16 + fq * 4 + j;
                int cc = wc * 64 + ni * 16 + fr;
                float v = acc[mi][ni][j];
                if (HAS_BIAS) v += bias[cc];
                if (OUT_BF16) ((unsigned short*)Cptr)[(size_t)rr * ldc + cc] = f2bf(v);
                else          ((float*)Cptr)[(size_t)rr * ldc + cc] = v;
            }
        }
    }
}

// ---------------- K^T/V partials ----------------
__global__ __launch_bounds__(256) void ktv_kernel(
    const unsigned short* __restrict__ QKV, float* __restrict__ part)
{
    const int ks = blockIdx.x;
    const int bh = blockIdx.y;
    const int b = bh >> 4, h = bh & 15;
    const unsigned short* Kbase = QKV + (size_t)(b * SEQ + ks * 256) * NQKV + 2048 + h * HD;
    const unsigned short* Vbase = QKV + (size_t)(b * SEQ + ks * 256) * NQKV + 4096 + h * HD;

    __shared__ __align__(16) unsigned short Ks_[64 * 128];
    __shared__ __align__(16) unsigned short Vs_[64 * 128];

    const int t  = threadIdx.x;
    const int l  = t & 63;
    const int w  = t >> 6;
    const int wr = w >> 1, wc = w & 1;
    const int fr = l & 15, fq = l >> 4;

    f32x4 acc[4][4] = {};

    const int srow = t >> 4;
    const int scol = (t & 15) * 8;

    for (int sc = 0; sc < 4; ++sc) {
        __syncthreads();
        #pragma unroll
        for (int r = 0; r < 4; ++r) {
            gld_lds16(Kbase + (size_t)(sc * 64 + r * 16 + srow) * NQKV + scol, &Ks_[(r * 16 + srow) * 128 + scol]);
            gld_lds16(Vbase + (size_t)(sc * 64 + r * 16 + srow) * NQKV + scol, &Vs_[(r * 16 + srow) * 128 + scol]);
        }
        __syncthreads();
        #pragma unroll
        for (int kk = 0; kk < 2; ++kk) {
            short8 a[4], bb[4];
            #pragma unroll
            for (int mi = 0; mi < 4; ++mi)
                #pragma unroll
                for (int i = 0; i < 8; ++i)
                    a[mi][i] = (short)Ks_[(kk * 32 + fq * 8 + i) * 128 + wr * 64 + mi * 16 + fr];
            #pragma unroll
            for (int ni = 0; ni < 4; ++ni)
                #pragma unroll
                for (int i = 0; i < 8; ++i)
                    bb[ni][i] = (short)Vs_[(kk * 32 + fq * 8 + i) * 128 + wc * 64 + ni * 16 + fr];
            #pragma unroll
            for (int mi = 0; mi < 4; ++mi)
                #pragma unroll
                for (int ni = 0; ni < 4; ++ni)
                    acc[mi][ni] = __builtin_amdgcn_mfma_f32_16x16x32_bf16(a[mi], bb[ni], acc[mi][ni], 0, 0, 0);
        }
    }

    float* base = part + ((size_t)bh * 8 + ks) * 16384;
    #pragma unroll
    for (int mi = 0; mi < 4; ++mi)
        #pragma unroll
        for (int ni = 0; ni < 4; ++ni)
            #pragma unroll
            for (int j = 0; j < 4; ++j)
                base[(wr * 64 + mi * 16 + fq * 4 + j) * 128 + wc * 64 + ni * 16 + fr] = acc[mi][ni][j];
}

// ---------------- reduce partials ----------------
__global__ void ktv_reduce(const float* __restrict__ part, unsigned short* __restrict__ M2t) {
    int idx = blockIdx.x * 256 + threadIdx.x;
    int bh = idx >> 14, rem = idx & 16383;
    const float* p = part + ((size_t)bh * 8) * 16384 + rem;
    float s = 0.f;
    #pragma unroll
    for (int k = 0; k < 8; ++k) s += p[(size_t)k * 16384];
    M2t[idx] = f2bf(s * 0.08838834764831845f);
}

// ---------------- W2 fold ----------------
__global__ __launch_bounds__(256) void w2_gemm(
    const unsigned short* __restrict__ Wo2, const unsigned short* __restrict__ M2t,
    unsigned short* __restrict__ W2)
{
    const int mt = blockIdx.x;
    const int bh = blockIdx.y;
    const int b = bh >> 4, h = bh & 15;
    const unsigned short* A = Wo2 + (size_t)(mt * 128) * DIMN + h * HD;
    const unsigned short* B = M2t + (size_t)bh * HD * HD;
    unsigned short* Cp = W2 + (size_t)b * DIMN * DIMN + (size_t)(mt * 128) * DIMN + h * HD;
    gemm_tile_core<1, 0>(A, DIMN, B, HD, nullptr, Cp, DIMN, HD);
}

extern "C" void kernel_launch(void* const* d_in, const int* in_sizes, int n_in,
                              void* d_out, int out_size, void* d_ws, size_t ws_size,
                              hipStream_t stream) {
    const float* x    = (const float*)d_in[0];
    const float* fcos = (const float*)d_in[1];
    const float* fsin = (const float*)d_in[2];
    const float* wq   = (const float*)d_in[3];
    const float* bq   = (const float*)d_in[4];
    const float* wk   = (const float*)d_in[5];
    const float* bk   = (const float*)d_in[6];
    const float* wv   = (const float*)d_in[7];
    const float* bv   = (const float*)d_in[8];
    const float* wo   = (const float*)d_in[9];
    const float* bo   = (const float*)d_in[10];
    float* out = (float*)d_out;

    char* ws = (char*)d_ws;
    size_t off = 0;
    auto alloc = [&](size_t bytes) { char* p = ws + off; off += (bytes + 255) & ~(size_t)255; return p; };

    unsigned short* Xb   = (unsigned short*)alloc((size_t)ROWS * DIMN * 2);
    unsigned short* Wcat = (unsigned short*)alloc((size_t)NQKV * DIMN * 2);
    unsigned short* Wo2  = (unsigned short*)alloc((size_t)DIMN * DIMN * 2);
    unsigned short* QKV  = (unsigned short*)alloc((size_t)ROWS * NQKV * 2);
    float*          part = (float*)alloc((size_t)32 * 8 * HD * HD * 4);
    unsigned short* M2t  = (unsigned short*)alloc((size_t)32 * HD * HD * 2);
    unsigned short* W2   = (unsigned short*)alloc((size_t)BSZ * DIMN * DIMN * 2);

    // all converts in one launch
    cvt_all<<<24576, 256, 0, stream>>>(x, wq, wk, wv, wo, Xb, Wcat, Wo2);

    // fused QKV projection + bias + RoPE  (M=4096, N=6144, K=2048): 384 blocks
    gemm256<0><<<384, 512, 0, stream>>>(
        Xb, DIMN, Wcat, DIMN, bq, bk, bv, fcos, fsin, QKV, NQKV, DIMN);

    // reassociated attention (no softmax): M2t = (K^T V)^T/sqrt(d) per (b,h)
    ktv_kernel<<<dim3(8, 32), 256, 0, stream>>>(QKV, part);
    ktv_reduce<<<(32 * 16384) / 256, 256, 0, stream>>>(part, M2t);

    // fold attention + output projection: W2_b = concat_h(Wo_h @ M2_{b,h})
    w2_gemm<<<dim3(16, 32), 256, 0, stream>>>(Wo2, M2t, W2);

    // out = Q @ W2_b^T + bo  (M=4096, N=2048 per batch, K=2048): 128 blocks
    gemm256<1><<<128, 512, 0, stream>>>(
        QKV, NQKV, W2, DIMN, bo, nullptr, nullptr, nullptr, nullptr, out, DIMN, DIMN);

    // ===== ABLATION probes (diagnostic; same grid/LDS/skeleton as QKV gemm256<0>) =====
    abl_stage<<<384, 512, 0, stream>>>(Xb, DIMN, Wcat, DIMN);
    abl_comp<<<384, 512, 0, stream>>>(part);
}

// Round 11
// 228.829 us; speedup vs baseline: 1.6071x; 1.6071x over previous
//
#include <hip/hip_runtime.h>
#include <hip/hip_bf16.h>

#define DIMN 2048
#define NQKV 6144
#define NH 16
#define HD 128
#define BSZ 2
#define SEQ 2048
#define ROWS (BSZ*SEQ)   // 4096

typedef short short8 __attribute__((ext_vector_type(8)));
typedef float f32x4 __attribute__((ext_vector_type(4)));

__device__ __forceinline__ unsigned short f2bf(float f) {
    __hip_bfloat16 h = __float2bfloat16(f);
    unsigned short u; __builtin_memcpy(&u, &h, 2); return u;
}

__device__ __forceinline__ void gld_lds16(const void* g, void* l) {
    __builtin_amdgcn_global_load_lds(
        (const __attribute__((address_space(1))) void*)g,
        (__attribute__((address_space(3))) void*)l, 16, 0, 0);
}

// ---------------- fused f32 -> bf16 converts ----------------
__global__ void cvt_all(const float* __restrict__ x, const float* __restrict__ wq,
                        const float* __restrict__ wk, const float* __restrict__ wv,
                        const float* __restrict__ wo,
                        unsigned short* __restrict__ Xb, unsigned short* __restrict__ Wcat,
                        unsigned short* __restrict__ Wo2) {
    int bid = blockIdx.x;
    const float* in; unsigned short* out; int base;
    if      (bid <  8192) { in = x;  out = Xb;             base = bid; }
    else if (bid < 12288) { in = wq; out = Wcat;           base = bid - 8192; }
    else if (bid < 16384) { in = wk; out = Wcat + 4194304; base = bid - 12288; }
    else if (bid < 20480) { in = wv; out = Wcat + 8388608; base = bid - 16384; }
    else                  { in = wo; out = Wo2;            base = bid - 20480; }
    int i = (base * 256 + threadIdx.x) * 4;
    float4 v = *(const float4*)(in + i);
    ushort4 o; o.x = f2bf(v.x); o.y = f2bf(v.y); o.z = f2bf(v.z); o.w = f2bf(v.w);
    *(ushort4*)(out + i) = o;
}

// ================= 256x256 GEMM, DE-CONVOYED: C[m][n] = sum_k A[m][k]*B[n][k] ===========
// r11 change (single structural variable vs r8): ONE barrier per K-tile (was 7).
// r10 ablation: stage-only + comp-only sum to 125us vs full 157us -> the lockstep
// sub-phase barriers serialized LDS-reads against MFMA (convoy). Now waves drift
// within a tile so one wave's ds_reads overlap another's MFMA.
// Race-freedom: each wave's final lgkmcnt(0) (before MM(1,0)) drains ALL its ds_reads
// before it reaches the tile barrier => staging (issued after the barrier, into buffer
// D^1 only, 1 tile ahead) can never collide with a pending read. vmcnt(0) at tile end
// is free: its loads were issued a full tile (~2800cy) earlier. WAR on reused aF is
// safe: in-order issue means consuming MFMAs issue before the overwriting ds_read.
// Everything else identical to r8 (swizzle, chunked XCD map, epilogue, 0 conflicts).

template<int MODE>
__global__ __launch_bounds__(512, 2) void gemm256(
    const unsigned short* __restrict__ A, int lda,
    const unsigned short* __restrict__ B, int ldb,
    const float* __restrict__ b0, const float* __restrict__ b1, const float* __restrict__ b2,
    const float* __restrict__ fcos, const float* __restrict__ fsin,
    void* __restrict__ C, int ldc, int K)
{
    __shared__ __align__(16) unsigned short As[32768];  // 64 KB: [2buf][2half][128][64]
    __shared__ __align__(16) unsigned short Bs[32768];  // 64 KB

    const int t  = threadIdx.x;
    const int l  = t & 63;
    const int w  = t >> 6;
    const int wr = w >> 2;          // 0..1
    const int wc = w & 3;           // 0..3
    const int fr = l & 15, fq = l >> 4;

    const int xcd = blockIdx.x & 7;
    const int j   = blockIdx.x >> 3;
    int mt, nt;
    if (MODE == 0) {
        if (j < 32) { mt = (xcd & 1) * 8 + (j >> 2); nt = (xcd >> 1) * 4 + (j & 3); }
        else { const int p = j - 32, c = xcd >> 1;
               mt = (c & 1) * 8 + (xcd & 1) * 4 + (p >> 2); nt = (4 + (c >> 1)) * 4 + (p & 3); }
    } else {
        mt = (xcd >> 1) * 4 + (j >> 2);
        nt = (xcd & 1) * 4 + (j & 3);
    }
    const int m0 = mt * 256;
    const int n0 = nt * 256;

    const unsigned short* Bsel = B;
    if (MODE == 1 && m0 >= 2048) Bsel += (size_t)2048 * 2048;  // per-batch W2

    const int srow = t >> 3;                        // 0..63
    const int scol = ((t & 7) ^ (srow & 7)) * 8;
    const unsigned short* aS = A    + (size_t)(m0 + srow) * lda + scol;
    const unsigned short* bS = Bsel + (size_t)(n0 + srow) * ldb + scol;

#define STG_A(KT, H) do { \
    const unsigned short* s_ = aS + (size_t)(H) * 128 * lda + (size_t)(KT) * 64; \
    gld_lds16(s_,                    &As[(((KT) & 1) << 14) + ((H) << 13) + t * 8]); \
    gld_lds16(s_ + (size_t)64 * lda, &As[(((KT) & 1) << 14) + ((H) << 13) + 4096 + t * 8]); \
  } while (0)
#define STG_B(KT, H) do { \
    const unsigned short* s_ = bS + (size_t)(H) * 128 * ldb + (size_t)(KT) * 64; \
    gld_lds16(s_,                    &Bs[(((KT) & 1) << 14) + ((H) << 13) + t * 8]); \
    gld_lds16(s_ + (size_t)64 * ldb, &Bs[(((KT) & 1) << 14) + ((H) << 13) + 4096 + t * 8]); \
  } while (0)

    const int cK0 = (fq ^ (fr & 7)) * 8;
    const int cK1 = ((4 + fq) ^ (fr & 7)) * 8;
    const int aB0 = wr * 8192 + fr * 64;
    const int bB0 = wc * 4096 + fr * 64;

    const unsigned aA0 = (unsigned)(size_t)&As[aB0 + cK0];
    const unsigned aA1 = (unsigned)(size_t)&As[aB0 + cK1];
    const unsigned bA0 = (unsigned)(size_t)&Bs[bB0 + cK0];
    const unsigned bA1 = (unsigned)(size_t)&Bs[bB0 + cK1];

    short8 aF[4][2], bF0[2][2], bF1[2][2];
    f32x4  acc[8][4] = {};

#define DSR(dst, areg, OFF) \
    asm volatile("ds_read_b128 %0, %1 offset:%2" : "=v"(dst) : "v"(areg), "n"(OFF))

#define RD_A(DDB, QM) do { \
    DSR(aF[0][0], aA0, (DDB) + (QM) * 8192 + 0);    DSR(aF[0][1], aA1, (DDB) + (QM) * 8192 + 0); \
    DSR(aF[1][0], aA0, (DDB) + (QM) * 8192 + 2048); DSR(aF[1][1], aA1, (DDB) + (QM) * 8192 + 2048); \
    DSR(aF[2][0], aA0, (DDB) + (QM) * 8192 + 4096); DSR(aF[2][1], aA1, (DDB) + (QM) * 8192 + 4096); \
    DSR(aF[3][0], aA0, (DDB) + (QM) * 8192 + 6144); DSR(aF[3][1], aA1, (DDB) + (QM) * 8192 + 6144); \
  } while (0)
#define RD_B(DDB, QN, BF) do { \
    DSR(BF[0][0], bA0, (DDB) + (QN) * 4096 + 0);    DSR(BF[0][1], bA1, (DDB) + (QN) * 4096 + 0); \
    DSR(BF[1][0], bA0, (DDB) + (QN) * 4096 + 2048); DSR(BF[1][1], bA1, (DDB) + (QN) * 4096 + 2048); \
  } while (0)

#define BAR() asm volatile("s_barrier" ::: "memory")

#define MM(QM, QN, BF) do { \
    _Pragma("unroll") for (int m2 = 0; m2 < 4; ++m2) \
      _Pragma("unroll") for (int n2 = 0; n2 < 2; ++n2) { \
        acc[(QM)*4+m2][(QN)*2+n2] = __builtin_amdgcn_mfma_f32_16x16x32_bf16( \
            aF[m2][0], BF[n2][0], acc[(QM)*4+m2][(QN)*2+n2], 0, 0, 0); \
        acc[(QM)*4+m2][(QN)*2+n2] = __builtin_amdgcn_mfma_f32_16x16x32_bf16( \
            aF[m2][1], BF[n2][1], acc[(QM)*4+m2][(QN)*2+n2], 0, 0, 0); } \
  } while (0)

// One K-tile: stage(t+1) -> 16 reads -> [lgkm(4)] MM00 -> [lgkm(0)] MM01 ->
// re-read A(QM1) -> [lgkm(0)] MM10+MM11 -> vmcnt(0) -> barrier.  NO mid-tile barriers.
#define TILE(KT, DDB) do { \
    if ((KT) + 1 < ktT) { \
        STG_A((KT) + 1, 0); STG_A((KT) + 1, 1); \
        STG_B((KT) + 1, 0); STG_B((KT) + 1, 1); \
    } \
    RD_A(DDB, 0); RD_B(DDB, 0, bF0); RD_B(DDB, 1, bF1); \
    asm volatile("s_waitcnt lgkmcnt(4)"); \
    __builtin_amdgcn_sched_barrier(0); \
    __builtin_amdgcn_s_setprio(1); \
    MM(0, 0, bF0); \
    asm volatile("s_waitcnt lgkmcnt(0)"); \
    __builtin_amdgcn_sched_barrier(0); \
    MM(0, 1, bF1); \
    __builtin_amdgcn_s_setprio(0); \
    RD_A(DDB, 1); \
    asm volatile("s_waitcnt lgkmcnt(0)"); \
    __builtin_amdgcn_sched_barrier(0); \
    __builtin_amdgcn_s_setprio(1); \
    MM(1, 0, bF0); MM(1, 1, bF1); \
    __builtin_amdgcn_s_setprio(0); \
    asm volatile("s_waitcnt vmcnt(0)"); \
    __builtin_amdgcn_sched_barrier(0); \
    BAR(); \
  } while (0)

    const int ktT = K >> 6;   // 32

    // prologue: stage tile 0 only; drain; barrier.
    STG_A(0, 0); STG_A(0, 1);
    STG_B(0, 0); STG_B(0, 1);
    asm volatile("s_waitcnt vmcnt(0)");
    __builtin_amdgcn_sched_barrier(0);
    BAR();

    for (int kt = 0; kt < ktT; kt += 2) {
        TILE(kt, 0);
        TILE(kt + 1, 32768);
    }

#undef TILE
#undef MM
#undef BAR
#undef RD_A
#undef RD_B
#undef DSR
#undef STG_A
#undef STG_B

    // ---- epilogue: bias (+ RoPE for MODE 0 on cols < 4096), store
    #pragma unroll
    for (int mi = 0; mi < 8; ++mi) {
        #pragma unroll
        for (int ni = 0; ni < 4; ++ni) {
            #pragma unroll
            for (int j2 = 0; j2 < 4; ++j2) {
                const int r  = m0 + wr * 128 + mi * 16 + fq * 4 + j2;
                const int cg = n0 + wc * 64 + ni * 16 + fr;
                float v = acc[mi][ni][j2];
                if (MODE == 0) {
                    v += (cg < 2048) ? b0[cg] : ((cg < 4096) ? b1[cg - 2048] : b2[cg - 4096]);
                    if (cg < 4096) {
                        const int s = r & (SEQ - 1);
                        const int i = (cg >> 1) & 63;
                        const float cs = fcos[s * 64 + i];
                        const float sn = fsin[s * 64 + i];
                        const float p  = __shfl_xor(v, 1);
                        v = (fr & 1) ? (p * sn + v * cs) : (v * cs - p * sn);
                    }
                    ((unsigned short*)C)[(size_t)r * ldc + cg] = f2bf(v);
                } else {
                    v += b0[cg];
                    ((float*)C)[(size_t)r * ldc + cg] = v;
                }
            }
        }
    }
}

// ---------------- 128x128 GEMM core (small GEMMs) ----------------
template<int OUT_BF16, int HAS_BIAS>
__device__ __forceinline__ void gemm_tile_core(
    const unsigned short* __restrict__ A, int lda,
    const unsigned short* __restrict__ B, int ldb,
    const float* __restrict__ bias,
    void* __restrict__ Cptr, int ldc, int K)
{
    __shared__ __align__(16) unsigned short As[128 * 64];
    __shared__ __align__(16) unsigned short Bs[128 * 64];

    const int t  = threadIdx.x;
    const int l  = t & 63;
    const int w  = t >> 6;
    const int wr = w >> 1, wc = w & 1;
    const int fr = l & 15, fq = l >> 4;

    f32x4 acc[4][4] = {};

    const int srow = t >> 3;
    const int scol = (t & 7) * 8;

    for (int k0 = 0; k0 < K; k0 += 64) {
        __syncthreads();
        #pragma unroll
        for (int r = 0; r < 4; ++r) {
            gld_lds16(A + (size_t)(r * 32 + srow) * lda + k0 + scol, &As[(r * 32 + srow) * 64 + scol]);
            gld_lds16(B + (size_t)(r * 32 + srow) * ldb + k0 + scol, &Bs[(r * 32 + srow) * 64 + scol]);
        }
        __syncthreads();
        #pragma unroll
        for (int kk = 0; kk < 2; ++kk) {
            short8 a[4], b[4];
            #pragma unroll
            for (int mi = 0; mi < 4; ++mi)
                a[mi] = *(const short8*)&As[(wr * 64 + mi * 16 + fr) * 64 + kk * 32 + fq * 8];
            #pragma unroll
            for (int ni = 0; ni < 4; ++ni)
                b[ni] = *(const short8*)&Bs[(wc * 64 + ni * 16 + fr) * 64 + kk * 32 + fq * 8];
            #pragma unroll
            for (int mi = 0; mi < 4; ++mi)
                #pragma unroll
                for (int ni = 0; ni < 4; ++ni)
                    acc[mi][ni] = __builtin_amdgcn_mfma_f32_16x16x32_bf16(a[mi], b[ni], acc[mi][ni], 0, 0, 0);
        }
    }

    #pragma unroll
    for (int mi = 0; mi < 4; ++mi) {
        #pragma unroll
        for (int ni = 0; ni < 4; ++ni) {
            #pragma unroll
            for (int j = 0; j < 4; ++j) {
                int rr = wr * 64 + mi * 16 + fq * 4 + j;
                int cc = wc * 64 + ni * 16 + fr;
                float v = acc[mi][ni][j];
                if (HAS_BIAS) v += bias[cc];
                if (OUT_BF16) ((unsigned short*)Cptr)[(size_t)rr * ldc + cc] = f2bf(v);
                else          ((float*)Cptr)[(size_t)rr * ldc + cc] = v;
            }
        }
    }
}

// ---------------- K^T/V partials ----------------
__global__ __launch_bounds__(256) void ktv_kernel(
    const unsigned short* __restrict__ QKV, float* __restrict__ part)
{
    const int ks = blockIdx.x;
    const int bh = blockIdx.y;
    const int b = bh >> 4, h = bh & 15;
    const unsigned short* Kbase = QKV + (size_t)(b * SEQ + ks * 256) * NQKV + 2048 + h * HD;
    const unsigned short* Vbase = QKV + (size_t)(b * SEQ + ks * 256) * NQKV + 4096 + h * HD;

    __shared__ __align__(16) unsigned short Ks_[64 * 128];
    __shared__ __align__(16) unsigned short Vs_[64 * 128];

    const int t  = threadIdx.x;
    const int l  = t & 63;
    const int w  = t >> 6;
    const int wr = w >> 1, wc = w & 1;
    const int fr = l & 15, fq = l >> 4;

    f32x4 acc[4][4] = {};

    const int srow = t >> 4;
    const int scol = (t & 15) * 8;

    for (int sc = 0; sc < 4; ++sc) {
        __syncthreads();
        #pragma unroll
        for (int r = 0; r < 4; ++r) {
            gld_lds16(Kbase + (size_t)(sc * 64 + r * 16 + srow) * NQKV + scol, &Ks_[(r * 16 + srow) * 128 + scol]);
            gld_lds16(Vbase + (size_t)(sc * 64 + r * 16 + srow) * NQKV + scol, &Vs_[(r * 16 + srow) * 128 + scol]);
        }
        __syncthreads();
        #pragma unroll
        for (int kk = 0; kk < 2; ++kk) {
            short8 a[4], bb[4];
            #pragma unroll
            for (int mi = 0; mi < 4; ++mi)
                #pragma unroll
                for (int i = 0; i < 8; ++i)
                    a[mi][i] = (short)Ks_[(kk * 32 + fq * 8 + i) * 128 + wr * 64 + mi * 16 + fr];
            #pragma unroll
            for (int ni = 0; ni < 4; ++ni)
                #pragma unroll
                for (int i = 0; i < 8; ++i)
                    bb[ni][i] = (short)Vs_[(kk * 32 + fq * 8 + i) * 128 + wc * 64 + ni * 16 + fr];
            #pragma unroll
            for (int mi = 0; mi < 4; ++mi)
                #pragma unroll
                for (int ni = 0; ni < 4; ++ni)
                    acc[mi][ni] = __builtin_amdgcn_mfma_f32_16x16x32_bf16(a[mi], bb[ni], acc[mi][ni], 0, 0, 0);
        }
    }

    float* base = part + ((size_t)bh * 8 + ks) * 16384;
    #pragma unroll
    for (int mi = 0; mi < 4; ++mi)
        #pragma unroll
        for (int ni = 0; ni < 4; ++ni)
            #pragma unroll
            for (int j = 0; j < 4; ++j)
                base[(wr * 64 + mi * 16 + fq * 4 + j) * 128 + wc * 64 + ni * 16 + fr] = acc[mi][ni][j];
}

// ---------------- reduce partials ----------------
__global__ void ktv_reduce(const float* __restrict__ part, unsigned short* __restrict__ M2t) {
    int idx = blockIdx.x * 256 + threadIdx.x;
    int bh = idx >> 14, rem = idx & 16383;
    const float* p = part + ((size_t)bh * 8) * 16384 + rem;
    float s = 0.f;
    #pragma unroll
    for (int k = 0; k < 8; ++k) s += p[(size_t)k * 16384];
    M2t[idx] = f2bf(s * 0.08838834764831845f);
}

// ---------------- W2 fold ----------------
__global__ __launch_bounds__(256) void w2_gemm(
    const unsigned short* __restrict__ Wo2, const unsigned short* __restrict__ M2t,
    unsigned short* __restrict__ W2)
{
    const int mt = blockIdx.x;
    const int bh = blockIdx.y;
    const int b = bh >> 4, h = bh & 15;
    const unsigned short* A = Wo2 + (size_t)(mt * 128) * DIMN + h * HD;
    const unsigned short* B = M2t + (size_t)bh * HD * HD;
    unsigned short* Cp = W2 + (size_t)b * DIMN * DIMN + (size_t)(mt * 128) * DIMN + h * HD;
    gemm_tile_core<1, 0>(A, DIMN, B, HD, nullptr, Cp, DIMN, HD);
}

extern "C" void kernel_launch(void* const* d_in, const int* in_sizes, int n_in,
                              void* d_out, int out_size, void* d_ws, size_t ws_size,
                              hipStream_t stream) {
    const float* x    = (const float*)d_in[0];
    const float* fcos = (const float*)d_in[1];
    const float* fsin = (const float*)d_in[2];
    const float* wq   = (const float*)d_in[3];
    const float* bq   = (const float*)d_in[4];
    const float* wk   = (const float*)d_in[5];
    const float* bk   = (const float*)d_in[6];
    const float* wv   = (const float*)d_in[7];
    const float* bv   = (const float*)d_in[8];
    const float* wo   = (const float*)d_in[9];
    const float* bo   = (const float*)d_in[10];
    float* out = (float*)d_out;

    char* ws = (char*)d_ws;
    size_t off = 0;
    auto alloc = [&](size_t bytes) { char* p = ws + off; off += (bytes + 255) & ~(size_t)255; return p; };

    unsigned short* Xb   = (unsigned short*)alloc((size_t)ROWS * DIMN * 2);
    unsigned short* Wcat = (unsigned short*)alloc((size_t)NQKV * DIMN * 2);
    unsigned short* Wo2  = (unsigned short*)alloc((size_t)DIMN * DIMN * 2);
    unsigned short* QKV  = (unsigned short*)alloc((size_t)ROWS * NQKV * 2);
    float*          part = (float*)alloc((size_t)32 * 8 * HD * HD * 4);
    unsigned short* M2t  = (unsigned short*)alloc((size_t)32 * HD * HD * 2);
    unsigned short* W2   = (unsigned short*)alloc((size_t)BSZ * DIMN * DIMN * 2);

    // all converts in one launch
    cvt_all<<<24576, 256, 0, stream>>>(x, wq, wk, wv, wo, Xb, Wcat, Wo2);

    // fused QKV projection + bias + RoPE  (M=4096, N=6144, K=2048): 384 blocks
    gemm256<0><<<384, 512, 0, stream>>>(
        Xb, DIMN, Wcat, DIMN, bq, bk, bv, fcos, fsin, QKV, NQKV, DIMN);

    // reassociated attention (no softmax): M2t = (K^T V)^T/sqrt(d) per (b,h)
    ktv_kernel<<<dim3(8, 32), 256, 0, stream>>>(QKV, part);
    ktv_reduce<<<(32 * 16384) / 256, 256, 0, stream>>>(part, M2t);

    // fold attention + output projection: W2_b = concat_h(Wo_h @ M2_{b,h})
    w2_gemm<<<dim3(16, 32), 256, 0, stream>>>(Wo2, M2t, W2);

    // out = Q @ W2_b^T + bo  (M=4096, N=2048 per batch, K=2048): 128 blocks
    gemm256<1><<<128, 512, 0, stream>>>(
        QKV, NQKV, W2, DIMN, bo, nullptr, nullptr, nullptr, nullptr, out, DIMN, DIMN);
}